// Round 1
// baseline (245.436 us; speedup 1.0000x reference)
//
#include <hip/hip_runtime.h>

// Problem shapes (fixed by setup_inputs):
//   x       [B=2, N=16, L=1024, E=512] f32
//   past_kv [2, 16, 64, 64] f32
//   Wq/Wk/Wv [64, 512], bq/bk/bv [64]
// Outputs (concat): out [2,16,1024,64] (group-normed), current_kv [2,16,1024,64,64]

constexpr int B  = 2;
constexpr int NH = 16;
constexpr int L  = 1024;
constexpr int E  = 512;
constexpr int D  = 64;
constexpr int M  = B * NH * L;   // 32768 rows
constexpr float EPS = 1e-5f;

// ---------------------------------------------------------------------------
// Kernel 1: QKV projection.  qkv[row, nb*64+col] = dot(x[row,:], W[col,:]) + b
// f32 tiled GEMM: BM=64, BN=64 (one of q/k/v per blockIdx.y), BK=32.
// ---------------------------------------------------------------------------
__global__ __launch_bounds__(256) void proj_kernel(
    const float* __restrict__ x,
    const float* __restrict__ Wq, const float* __restrict__ Wk,
    const float* __restrict__ Wv,
    const float* __restrict__ bq, const float* __restrict__ bk,
    const float* __restrict__ bv,
    float* __restrict__ qkv)   // [M, 192]
{
    constexpr int BM = 64, BK = 32;
    // transposed tiles: [k][row/col], padded to 68 floats (16B-aligned rows,
    // bank offset 68%32=4 spreads banks)
    __shared__ float xs[BK][BM + 4];
    __shared__ float ws[BK][BM + 4];

    const int mb = blockIdx.x;          // 0..511
    const int nb = blockIdx.y;          // 0: q, 1: k, 2: v
    const float* W    = (nb == 0) ? Wq : (nb == 1) ? Wk : Wv;
    const float* bias = (nb == 0) ? bq : (nb == 1) ? bk : bv;

    const int tid = threadIdx.x;
    const int ty  = tid >> 4;           // 0..15 -> row group
    const int tx  = tid & 15;           // 0..15 -> col group
    const int row0 = mb * BM;

    // staging mapping: lr = tid>>3 (0..31), kc = (tid&7)*4
    const int lr = tid >> 3;
    const int kc = (tid & 7) * 4;

    float acc[4][4] = {};

    for (int k0 = 0; k0 < E; k0 += BK) {
        float4 a0 = *(const float4*)&x[(size_t)(row0 + lr) * E + k0 + kc];
        float4 a1 = *(const float4*)&x[(size_t)(row0 + lr + 32) * E + k0 + kc];
        float4 w0 = *(const float4*)&W[(size_t)lr * E + k0 + kc];
        float4 w1 = *(const float4*)&W[(size_t)(lr + 32) * E + k0 + kc];
        __syncthreads();   // previous tile fully consumed
        xs[kc + 0][lr] = a0.x; xs[kc + 1][lr] = a0.y;
        xs[kc + 2][lr] = a0.z; xs[kc + 3][lr] = a0.w;
        xs[kc + 0][lr + 32] = a1.x; xs[kc + 1][lr + 32] = a1.y;
        xs[kc + 2][lr + 32] = a1.z; xs[kc + 3][lr + 32] = a1.w;
        ws[kc + 0][lr] = w0.x; ws[kc + 1][lr] = w0.y;
        ws[kc + 2][lr] = w0.z; ws[kc + 3][lr] = w0.w;
        ws[kc + 0][lr + 32] = w1.x; ws[kc + 1][lr + 32] = w1.y;
        ws[kc + 2][lr + 32] = w1.z; ws[kc + 3][lr + 32] = w1.w;
        __syncthreads();

        #pragma unroll
        for (int kk = 0; kk < BK; ++kk) {
            float4 av = *(const float4*)&xs[kk][ty * 4];
            float4 bv4 = *(const float4*)&ws[kk][tx * 4];
            float a[4] = {av.x, av.y, av.z, av.w};
            float b[4] = {bv4.x, bv4.y, bv4.z, bv4.w};
            #pragma unroll
            for (int i = 0; i < 4; ++i)
                #pragma unroll
                for (int j = 0; j < 4; ++j)
                    acc[i][j] = fmaf(a[i], b[j], acc[i][j]);
        }
    }

    // epilogue: add bias, write [row, nb*64 + col]
    const float4 bb = *(const float4*)&bias[tx * 4];
    #pragma unroll
    for (int i = 0; i < 4; ++i) {
        float4 o;
        o.x = acc[i][0] + bb.x; o.y = acc[i][1] + bb.y;
        o.z = acc[i][2] + bb.z; o.w = acc[i][3] + bb.w;
        *(float4*)&qkv[(size_t)(row0 + ty * 4 + i) * 192 + nb * 64 + tx * 4] = o;
    }
}

// ---------------------------------------------------------------------------
// Kernel 2: fused retention. One block per (b,n,l).
//   current_kv[bnl, kd, vd] = decay*past_kv[bn,kd,vd] + k[kd]*v[vd]
//   out_pre[bnl, v] = decay * (q @ past_kv)[v] + (q.k) * v[v]
//   partials[bnl] = (sum out_pre, sum out_pre^2)
// ---------------------------------------------------------------------------
__global__ __launch_bounds__(256) void retention_kernel(
    const float* __restrict__ qkv,      // [M,192]
    const float* __restrict__ past_kv,  // [B*NH, 64, 64]
    float* __restrict__ out_pre,        // [M,64]
    float* __restrict__ ckv,            // [M,4096]
    float* __restrict__ partials)       // [M,2]
{
    const int bnl = blockIdx.x;
    const int bn  = bnl >> 10;
    const int h   = bn & (NH - 1);
    const int tid = threadIdx.x;
    const float decay = 1.0f - exp2f(-5.0f - (float)h);

    __shared__ float q_s[64], k_s[64], v_s[64];
    __shared__ float qk_s;

    if (tid < 192) {
        float val = qkv[(size_t)bnl * 192 + tid];
        if (tid < 64)       q_s[tid]       = val;
        else if (tid < 128) k_s[tid - 64]  = val;
        else                v_s[tid - 128] = val;
    }
    __syncthreads();

    if (tid < 64) {
        float p = q_s[tid] * k_s[tid];
        #pragma unroll
        for (int off = 32; off; off >>= 1) p += __shfl_down(p, off);
        if (tid == 0) qk_s = p;
    }
    __syncthreads();
    const float qk = qk_s;

    const float* pkv = past_kv + (size_t)bn * 4096;
    float* ckv_o = ckv + (size_t)bnl * 4096;

    #pragma unroll
    for (int i = 0; i < 16; ++i) {
        int idx = i * 256 + tid;
        int kd = idx >> 6, vd = idx & 63;
        ckv_o[idx] = fmaf(decay, pkv[idx], k_s[kd] * v_s[vd]);
    }

    float o = 0.0f;
    if (tid < 64) {
        float s = 0.0f;
        #pragma unroll 8
        for (int kd = 0; kd < 64; ++kd)
            s = fmaf(q_s[kd], pkv[kd * 64 + tid], s);
        o = fmaf(decay, s, qk * v_s[tid]);
        out_pre[(size_t)bnl * 64 + tid] = o;
    }

    if (tid < 64) {
        float s1 = o, s2 = o * o;
        #pragma unroll
        for (int off = 32; off; off >>= 1) {
            s1 += __shfl_down(s1, off);
            s2 += __shfl_down(s2, off);
        }
        if (tid == 0) {
            partials[(size_t)bnl * 2]     = s1;
            partials[(size_t)bnl * 2 + 1] = s2;
        }
    }
}

// ---------------------------------------------------------------------------
// Kernel 3: per-group (b,n) reduction of partials -> mean, rstd
// ---------------------------------------------------------------------------
__global__ __launch_bounds__(256) void group_reduce_kernel(
    const float* __restrict__ partials,  // [M,2]
    float* __restrict__ stats)           // [32,2]
{
    const int g   = blockIdx.x;   // 0..31
    const int tid = threadIdx.x;
    float s1 = 0.0f, s2 = 0.0f;
    for (int i = tid; i < 1024; i += 256) {
        s1 += partials[(size_t)(g * 1024 + i) * 2];
        s2 += partials[(size_t)(g * 1024 + i) * 2 + 1];
    }
    __shared__ float r1[256], r2[256];
    r1[tid] = s1; r2[tid] = s2;
    __syncthreads();
    for (int off = 128; off; off >>= 1) {
        if (tid < off) { r1[tid] += r1[tid + off]; r2[tid] += r2[tid + off]; }
        __syncthreads();
    }
    if (tid == 0) {
        const float cnt = (float)(L * D);   // 65536
        float mean = r1[0] / cnt;
        float var  = r2[0] / cnt - mean * mean;
        stats[g * 2]     = mean;
        stats[g * 2 + 1] = rsqrtf(var + EPS);
    }
}

// ---------------------------------------------------------------------------
// Kernel 4: in-place normalize of out
// ---------------------------------------------------------------------------
__global__ __launch_bounds__(256) void normalize_kernel(
    float* __restrict__ out, const float* __restrict__ stats)
{
    int idx = blockIdx.x * 256 + threadIdx.x;   // 0 .. M*64-1
    int g = idx >> 16;                          // 65536 elems per group
    float mean = stats[g * 2];
    float rstd = stats[g * 2 + 1];
    out[idx] = (out[idx] - mean) * rstd;
}

// ---------------------------------------------------------------------------
extern "C" void kernel_launch(void* const* d_in, const int* in_sizes, int n_in,
                              void* d_out, int out_size, void* d_ws, size_t ws_size,
                              hipStream_t stream)
{
    const float* x       = (const float*)d_in[0];
    const float* past_kv = (const float*)d_in[1];
    const float* Wq      = (const float*)d_in[2];
    const float* bq      = (const float*)d_in[3];
    const float* Wk      = (const float*)d_in[4];
    const float* bk      = (const float*)d_in[5];
    const float* Wv      = (const float*)d_in[6];
    const float* bv      = (const float*)d_in[7];

    float* out = (float*)d_out;                    // [M*64]
    float* ckv = out + (size_t)M * 64;             // [M*4096]

    float* qkv      = (float*)d_ws;                // M*192 floats = 25.2 MB
    float* partials = qkv + (size_t)M * 192;       // M*2 floats
    float* stats    = partials + (size_t)M * 2;    // 64 floats

    proj_kernel<<<dim3(M / 64, 3), 256, 0, stream>>>(x, Wq, Wk, Wv, bq, bk, bv, qkv);
    retention_kernel<<<M, 256, 0, stream>>>(qkv, past_kv, out, ckv, partials);
    group_reduce_kernel<<<32, 256, 0, stream>>>(partials, stats);
    normalize_kernel<<<(M * 64) / 256, 256, 0, stream>>>(out, stats);
}

// Round 2
// 171.079 us; speedup vs baseline: 1.4346x; 1.4346x over previous
//
#include <hip/hip_runtime.h>

// Shapes: x[2,16,1024,512] f32, past_kv[2,16,64,64] f32, Wq/Wk/Wv[64,512], b*[64]
// Outputs (concat): out[2,16,1024,64] (group-normed), current_kv[2,16,1024,64,64]

constexpr int B  = 2;
constexpr int NH = 16;
constexpr int L  = 1024;
constexpr int E  = 512;
constexpr int D  = 64;
constexpr int M  = B * NH * L;     // 32768 rows
constexpr int NQKV = 192;
constexpr float EPS = 1e-5f;

using short8 = __attribute__((ext_vector_type(8))) short;
using f32x4  = __attribute__((ext_vector_type(4))) float;

__device__ __forceinline__ unsigned short f2bf(float f) {
    union { float f; unsigned int u; } x; x.f = f;
    unsigned int u = x.u;
    return (unsigned short)((u + 0x7fffu + ((u >> 16) & 1u)) >> 16);
}

// ---------------------------------------------------------------------------
// Kernel 0: convert Wq|Wk|Wv (each 64x512 f32) -> Wb bf16 [192][512]
// ---------------------------------------------------------------------------
__global__ __launch_bounds__(256) void convw_kernel(
    const float* __restrict__ Wq, const float* __restrict__ Wk,
    const float* __restrict__ Wv, unsigned short* __restrict__ Wb)
{
    int idx = blockIdx.x * 256 + threadIdx.x;      // float4 index, 0..24575
    const float* src = (idx < 8192) ? Wq : (idx < 16384) ? Wk : Wv;
    int off = idx & 8191;
    float4 v = ((const float4*)src)[off];
    unsigned short o[4] = {f2bf(v.x), f2bf(v.y), f2bf(v.z), f2bf(v.w)};
    Wb[(size_t)idx * 4 + 0] = o[0];
    Wb[(size_t)idx * 4 + 1] = o[1];
    Wb[(size_t)idx * 4 + 2] = o[2];
    Wb[(size_t)idx * 4 + 3] = o[3];
}

// ---------------------------------------------------------------------------
// Kernel 1: QKV projection via bf16 MFMA.
// C[M,192] = X[M,512] * Wb^T + bias.  BM=128, BN=192(all), BK=64.
// 512 threads = 8 waves (2x4); each wave computes 64x48 via 4x3 16x16 frags.
// ---------------------------------------------------------------------------
__global__ __launch_bounds__(512) void proj_mfma_kernel(
    const float* __restrict__ x, const unsigned short* __restrict__ Wb,
    const float* __restrict__ bq, const float* __restrict__ bk,
    const float* __restrict__ bv,
    float* __restrict__ qkv)
{
    constexpr int BM = 128, BK = 64, LDP = 72;   // +8 bf16 pad: 2-way banks only
    __shared__ unsigned short Xs[BM][LDP];
    __shared__ unsigned short Ws[NQKV][LDP];
    __shared__ float bias_s[NQKV];

    const int tid  = threadIdx.x;
    const int row0 = blockIdx.x * BM;
    if (tid < NQKV)
        bias_s[tid] = (tid < 64) ? bq[tid] : (tid < 128) ? bk[tid - 64] : bv[tid - 128];

    const int wid  = tid >> 6;
    const int lane = tid & 63;
    const int wr   = wid >> 2;            // 0..1  -> row half
    const int wc   = wid & 3;             // 0..3  -> col block of 48
    const int l15  = lane & 15;
    const int lk   = (lane >> 4) * 8;     // k sub-offset 0,8,16,24

    const int xr = tid >> 2;              // 0..127 staging row
    const int xc = (tid & 3) * 16;        // staging col (f32 elems)

    f32x4 acc[4][3] = {};

    for (int k0 = 0; k0 < E; k0 += BK) {
        float4 xa[4];
        #pragma unroll
        for (int i = 0; i < 4; ++i)
            xa[i] = *(const float4*)&x[(size_t)(row0 + xr) * E + k0 + xc + i * 4];
        short8 wch[3];
        #pragma unroll
        for (int i = 0; i < 3; ++i) {
            int c = tid + i * 512;               // chunk 0..1535
            wch[i] = *(const short8*)&Wb[(size_t)(c >> 3) * E + k0 + (c & 7) * 8];
        }
        __syncthreads();   // previous tile fully consumed
        unsigned short tmp[16];
        #pragma unroll
        for (int i = 0; i < 4; ++i) {
            tmp[i*4+0] = f2bf(xa[i].x); tmp[i*4+1] = f2bf(xa[i].y);
            tmp[i*4+2] = f2bf(xa[i].z); tmp[i*4+3] = f2bf(xa[i].w);
        }
        *(short8*)&Xs[xr][xc]     = *(short8*)&tmp[0];
        *(short8*)&Xs[xr][xc + 8] = *(short8*)&tmp[8];
        #pragma unroll
        for (int i = 0; i < 3; ++i) {
            int c = tid + i * 512;
            *(short8*)&Ws[c >> 3][(c & 7) * 8] = wch[i];
        }
        __syncthreads();

        #pragma unroll
        for (int kk = 0; kk < 2; ++kk) {
            short8 a[4], b[3];
            #pragma unroll
            for (int mi = 0; mi < 4; ++mi)
                a[mi] = *(const short8*)&Xs[wr * 64 + mi * 16 + l15][kk * 32 + lk];
            #pragma unroll
            for (int ni = 0; ni < 3; ++ni)
                b[ni] = *(const short8*)&Ws[wc * 48 + ni * 16 + l15][kk * 32 + lk];
            #pragma unroll
            for (int mi = 0; mi < 4; ++mi)
                #pragma unroll
                for (int ni = 0; ni < 3; ++ni)
                    acc[mi][ni] = __builtin_amdgcn_mfma_f32_16x16x32_bf16(
                        a[mi], b[ni], acc[mi][ni], 0, 0, 0);
        }
    }

    // epilogue: C/D map col=lane&15, row=(lane>>4)*4+j
    #pragma unroll
    for (int mi = 0; mi < 4; ++mi) {
        #pragma unroll
        for (int ni = 0; ni < 3; ++ni) {
            int col = wc * 48 + ni * 16 + l15;
            float bb = bias_s[col];
            #pragma unroll
            for (int j = 0; j < 4; ++j) {
                int row = wr * 64 + mi * 16 + (lane >> 4) * 4 + j;
                qkv[(size_t)(row0 + row) * NQKV + col] = acc[mi][ni][j] + bb;
            }
        }
    }
}

// ---------------------------------------------------------------------------
// Kernel 2: fused retention (float4 I/O). One block per (b,n,l).
// ---------------------------------------------------------------------------
__global__ __launch_bounds__(256) void retention_kernel(
    const float* __restrict__ qkv,      // [M,192]
    const float* __restrict__ past_kv,  // [B*NH, 64, 64]
    float* __restrict__ out_pre,        // [M,64]
    float* __restrict__ ckv,            // [M,4096]
    float* __restrict__ partials)       // [M,2]
{
    const int bnl = blockIdx.x;
    const int bn  = bnl >> 10;
    const int h   = bn & (NH - 1);
    const int tid = threadIdx.x;
    const float decay = 1.0f - exp2f(-5.0f - (float)h);

    __shared__ float q_s[64], k_s[64], v_s[64];
    __shared__ float qk_s;

    if (tid < 48) {
        float4 val = *(const float4*)&qkv[(size_t)bnl * 192 + tid * 4];
        if (tid < 16)      *(float4*)&q_s[tid * 4]        = val;
        else if (tid < 32) *(float4*)&k_s[(tid - 16) * 4] = val;
        else               *(float4*)&v_s[(tid - 32) * 4] = val;
    }
    __syncthreads();

    if (tid < 64) {
        float p = q_s[tid] * k_s[tid];
        #pragma unroll
        for (int off = 32; off; off >>= 1) p += __shfl_down(p, off);
        if (tid == 0) qk_s = p;
    }
    __syncthreads();
    const float qk = qk_s;

    const float* pkv = past_kv + (size_t)bn * 4096;
    float* co = ckv + (size_t)bnl * 4096;

    #pragma unroll
    for (int i = 0; i < 4; ++i) {
        int e  = i * 256 + tid;        // float4 index 0..1023
        int kd = e >> 4;
        int vd = (e & 15) * 4;
        float kk = k_s[kd];
        float4 p  = *(const float4*)&pkv[e * 4];
        float4 vv = *(const float4*)&v_s[vd];
        float4 r;
        r.x = fmaf(decay, p.x, kk * vv.x);
        r.y = fmaf(decay, p.y, kk * vv.y);
        r.z = fmaf(decay, p.z, kk * vv.z);
        r.w = fmaf(decay, p.w, kk * vv.w);
        *(float4*)&co[e * 4] = r;
    }

    float o = 0.0f;
    if (tid < 64) {
        float s = 0.0f;
        #pragma unroll 8
        for (int kd = 0; kd < 64; ++kd)
            s = fmaf(q_s[kd], pkv[kd * 64 + tid], s);
        o = fmaf(decay, s, qk * v_s[tid]);
        out_pre[(size_t)bnl * 64 + tid] = o;

        float s1 = o, s2 = o * o;
        #pragma unroll
        for (int off = 32; off; off >>= 1) {
            s1 += __shfl_down(s1, off);
            s2 += __shfl_down(s2, off);
        }
        if (tid == 0) {
            partials[(size_t)bnl * 2]     = s1;
            partials[(size_t)bnl * 2 + 1] = s2;
        }
    }
}

// ---------------------------------------------------------------------------
// Kernel 3: per-group (b,n) reduction of partials -> mean, rstd
// ---------------------------------------------------------------------------
__global__ __launch_bounds__(256) void group_reduce_kernel(
    const float* __restrict__ partials, float* __restrict__ stats)
{
    const int g   = blockIdx.x;
    const int tid = threadIdx.x;
    float s1 = 0.0f, s2 = 0.0f;
    for (int i = tid; i < 1024; i += 256) {
        s1 += partials[(size_t)(g * 1024 + i) * 2];
        s2 += partials[(size_t)(g * 1024 + i) * 2 + 1];
    }
    __shared__ float r1[256], r2[256];
    r1[tid] = s1; r2[tid] = s2;
    __syncthreads();
    for (int off = 128; off; off >>= 1) {
        if (tid < off) { r1[tid] += r1[tid + off]; r2[tid] += r2[tid + off]; }
        __syncthreads();
    }
    if (tid == 0) {
        const float cnt = (float)(L * D);
        float mean = r1[0] / cnt;
        float var  = r2[0] / cnt - mean * mean;
        stats[g * 2]     = mean;
        stats[g * 2 + 1] = rsqrtf(var + EPS);
    }
}

// ---------------------------------------------------------------------------
// Kernel 4: in-place normalize (float4)
// ---------------------------------------------------------------------------
__global__ __launch_bounds__(256) void normalize_kernel(
    float* __restrict__ out, const float* __restrict__ stats)
{
    int idx = blockIdx.x * 256 + threadIdx.x;   // float4 index, 0..M*16-1
    int g = idx >> 14;                          // 16384 float4 per group
    float mean = stats[g * 2];
    float rstd = stats[g * 2 + 1];
    float4 v = ((const float4*)out)[idx];
    v.x = (v.x - mean) * rstd; v.y = (v.y - mean) * rstd;
    v.z = (v.z - mean) * rstd; v.w = (v.w - mean) * rstd;
    ((float4*)out)[idx] = v;
}

// ---------------------------------------------------------------------------
extern "C" void kernel_launch(void* const* d_in, const int* in_sizes, int n_in,
                              void* d_out, int out_size, void* d_ws, size_t ws_size,
                              hipStream_t stream)
{
    const float* x       = (const float*)d_in[0];
    const float* past_kv = (const float*)d_in[1];
    const float* Wq      = (const float*)d_in[2];
    const float* bq      = (const float*)d_in[3];
    const float* Wk      = (const float*)d_in[4];
    const float* bk      = (const float*)d_in[5];
    const float* Wv      = (const float*)d_in[6];
    const float* bv      = (const float*)d_in[7];

    float* out = (float*)d_out;                    // [M*64]
    float* ckv = out + (size_t)M * 64;             // [M*4096]

    // Wb (bf16 weights, 192*512 ushorts) lives in the TAIL of the ckv output
    // region: proj reads it before retention overwrites that region (stream
    // order guarantees this). Zero extra ws.
    unsigned short* Wb = (unsigned short*)(ckv + (size_t)M * 4096) - (size_t)NQKV * E;

    float* qkv      = (float*)d_ws;                // M*192 floats
    float* partials = qkv + (size_t)M * 192;       // M*2
    float* stats    = partials + (size_t)M * 2;    // 64

    convw_kernel<<<96, 256, 0, stream>>>(Wq, Wk, Wv, Wb);
    proj_mfma_kernel<<<M / 128, 512, 0, stream>>>(x, Wb, bq, bk, bv, qkv);
    retention_kernel<<<M, 256, 0, stream>>>(qkv, past_kv, out, ckv, partials);
    group_reduce_kernel<<<32, 256, 0, stream>>>(partials, stats);
    normalize_kernel<<<(M * 16) / 256, 256, 0, stream>>>(out, stats);
}

// Round 3
// 146.805 us; speedup vs baseline: 1.6719x; 1.1654x over previous
//
#include <hip/hip_runtime.h>

// Shapes: x[2,16,1024,512] f32, past_kv[2,16,64,64] f32, Wq/Wk/Wv[64,512], b*[64]
// Outputs (concat): out[2,16,1024,64] (group-normed), current_kv[2,16,1024,64,64]

constexpr int B  = 2;
constexpr int NH = 16;
constexpr int L  = 1024;
constexpr int E  = 512;
constexpr int D  = 64;
constexpr int M  = B * NH * L;     // 32768 rows
constexpr int NQKV = 192;
constexpr int BLK = 16;            // positions per retention block
constexpr int NBLKS = M / BLK;     // 2048
constexpr float EPS = 1e-5f;

using short8 = __attribute__((ext_vector_type(8))) short;
using f32x4  = __attribute__((ext_vector_type(4))) float;

__device__ __forceinline__ unsigned short f2bf(float f) {
    union { float f; unsigned int u; } x; x.f = f;
    unsigned int u = x.u;
    return (unsigned short)((u + 0x7fffu + ((u >> 16) & 1u)) >> 16);
}

// ---------------------------------------------------------------------------
// Kernel 0: convert Wq|Wk|Wv (each 64x512 f32) -> Wb bf16 [192][512]
// ---------------------------------------------------------------------------
__global__ __launch_bounds__(256) void convw_kernel(
    const float* __restrict__ Wq, const float* __restrict__ Wk,
    const float* __restrict__ Wv, unsigned short* __restrict__ Wb)
{
    int idx = blockIdx.x * 256 + threadIdx.x;      // float4 index, 0..24575
    const float* src = (idx < 8192) ? Wq : (idx < 16384) ? Wk : Wv;
    int off = idx & 8191;
    float4 v = ((const float4*)src)[off];
    unsigned short o[4] = {f2bf(v.x), f2bf(v.y), f2bf(v.z), f2bf(v.w)};
    Wb[(size_t)idx * 4 + 0] = o[0];
    Wb[(size_t)idx * 4 + 1] = o[1];
    Wb[(size_t)idx * 4 + 2] = o[2];
    Wb[(size_t)idx * 4 + 3] = o[3];
}

// ---------------------------------------------------------------------------
// Kernel 1: QKV projection via bf16 MFMA.
// C[M,192] = X[M,512] * Wb^T + bias.  BM=128, BN=192(all), BK=64.
// ---------------------------------------------------------------------------
__global__ __launch_bounds__(512) void proj_mfma_kernel(
    const float* __restrict__ x, const unsigned short* __restrict__ Wb,
    const float* __restrict__ bq, const float* __restrict__ bk,
    const float* __restrict__ bv,
    float* __restrict__ qkv)
{
    constexpr int BM = 128, BK = 64, LDP = 72;
    __shared__ unsigned short Xs[BM][LDP];
    __shared__ unsigned short Ws[NQKV][LDP];
    __shared__ float bias_s[NQKV];

    const int tid  = threadIdx.x;
    const int row0 = blockIdx.x * BM;
    if (tid < NQKV)
        bias_s[tid] = (tid < 64) ? bq[tid] : (tid < 128) ? bk[tid - 64] : bv[tid - 128];

    const int wid  = tid >> 6;
    const int lane = tid & 63;
    const int wr   = wid >> 2;
    const int wc   = wid & 3;
    const int l15  = lane & 15;
    const int lk   = (lane >> 4) * 8;

    const int xr = tid >> 2;
    const int xc = (tid & 3) * 16;

    f32x4 acc[4][3] = {};

    for (int k0 = 0; k0 < E; k0 += BK) {
        float4 xa[4];
        #pragma unroll
        for (int i = 0; i < 4; ++i)
            xa[i] = *(const float4*)&x[(size_t)(row0 + xr) * E + k0 + xc + i * 4];
        short8 wch[3];
        #pragma unroll
        for (int i = 0; i < 3; ++i) {
            int c = tid + i * 512;
            wch[i] = *(const short8*)&Wb[(size_t)(c >> 3) * E + k0 + (c & 7) * 8];
        }
        __syncthreads();
        unsigned short tmp[16];
        #pragma unroll
        for (int i = 0; i < 4; ++i) {
            tmp[i*4+0] = f2bf(xa[i].x); tmp[i*4+1] = f2bf(xa[i].y);
            tmp[i*4+2] = f2bf(xa[i].z); tmp[i*4+3] = f2bf(xa[i].w);
        }
        *(short8*)&Xs[xr][xc]     = *(short8*)&tmp[0];
        *(short8*)&Xs[xr][xc + 8] = *(short8*)&tmp[8];
        #pragma unroll
        for (int i = 0; i < 3; ++i) {
            int c = tid + i * 512;
            *(short8*)&Ws[c >> 3][(c & 7) * 8] = wch[i];
        }
        __syncthreads();

        #pragma unroll
        for (int kk = 0; kk < 2; ++kk) {
            short8 a[4], b[3];
            #pragma unroll
            for (int mi = 0; mi < 4; ++mi)
                a[mi] = *(const short8*)&Xs[wr * 64 + mi * 16 + l15][kk * 32 + lk];
            #pragma unroll
            for (int ni = 0; ni < 3; ++ni)
                b[ni] = *(const short8*)&Ws[wc * 48 + ni * 16 + l15][kk * 32 + lk];
            #pragma unroll
            for (int mi = 0; mi < 4; ++mi)
                #pragma unroll
                for (int ni = 0; ni < 3; ++ni)
                    acc[mi][ni] = __builtin_amdgcn_mfma_f32_16x16x32_bf16(
                        a[mi], b[ni], acc[mi][ni], 0, 0, 0);
        }
    }

    #pragma unroll
    for (int mi = 0; mi < 4; ++mi) {
        #pragma unroll
        for (int ni = 0; ni < 3; ++ni) {
            int col = wc * 48 + ni * 16 + l15;
            float bb = bias_s[col];
            #pragma unroll
            for (int j = 0; j < 4; ++j) {
                int row = wr * 64 + mi * 16 + (lane >> 4) * 4 + j;
                qkv[(size_t)(row0 + row) * NQKV + col] = acc[mi][ni][j] + bb;
            }
        }
    }
}

// ---------------------------------------------------------------------------
// Kernel 2: fused retention, 16 positions per block.
//   pkv staged once in LDS + registers; ckv = decay*pkv + k (x) v;
//   out_pre = decay*(q@pkv) + (q.k)*v;  per-block groupnorm partials.
// ---------------------------------------------------------------------------
__global__ __launch_bounds__(256) void retention_kernel(
    const float* __restrict__ qkv,      // [M,192]
    const float* __restrict__ past_kv,  // [B*NH, 64, 64]
    float* __restrict__ out_pre,        // [M,64]
    float* __restrict__ ckv,            // [M,4096]
    float* __restrict__ partials)       // [NBLKS,2]
{
    const int blk  = blockIdx.x;
    const int bn   = blk >> 6;             // 64 blocks per (b,n)
    const int pos0 = (blk & 63) * BLK;
    const int h    = bn & (NH - 1);
    const int tid  = threadIdx.x;
    const float decay = 1.0f - exp2f(-5.0f - (float)h);

    __shared__ float pkv_s[64 * 64];        // [kd][vd] 16 KB
    __shared__ float qkv_s[BLK * NQKV];     // [pos][q|k|v] 12 KB
    __shared__ float qk_s[BLK];
    __shared__ float r1[256], r2[256];

    const float* pkv = past_kv + (size_t)bn * 4096;
    #pragma unroll
    for (int j = 0; j < 4; ++j) {
        int f = tid + j * 256;
        *(float4*)&pkv_s[f * 4] = *(const float4*)&pkv[f * 4];
    }
    const float* qrow = qkv + (size_t)(bn * L + pos0) * NQKV;
    #pragma unroll
    for (int j = 0; j < 3; ++j) {
        int f = tid + j * 256;
        *(float4*)&qkv_s[f * 4] = *(const float4*)&qrow[f * 4];
    }
    __syncthreads();

    // q.k per position: threads tid -> pos=tid>>4, chunk c=tid&15 (4 elems)
    {
        int pos = tid >> 4, c = tid & 15;
        const float* qp = &qkv_s[pos * NQKV];
        float p = 0.0f;
        #pragma unroll
        for (int j = 0; j < 4; ++j)
            p = fmaf(qp[c * 4 + j], qp[64 + c * 4 + j], p);
        p += __shfl_xor(p, 1); p += __shfl_xor(p, 2);
        p += __shfl_xor(p, 4); p += __shfl_xor(p, 8);
        if (c == 0) qk_s[pos] = p;
    }

    // pkv quads for this thread's store slots (reused across 16 positions)
    float4 p4[4];
    #pragma unroll
    for (int j = 0; j < 4; ++j)
        p4[j] = *(const float4*)&pkv_s[(tid + j * 256) * 4];
    __syncthreads();

    // ckv writes: 16 pos x 16 KB contiguous
    float* co = ckv + (size_t)(bn * L + pos0) * 4096;
    for (int pos = 0; pos < BLK; ++pos) {
        const float* ks = &qkv_s[pos * NQKV + 64];
        const float* vs = &qkv_s[pos * NQKV + 128];
        #pragma unroll
        for (int j = 0; j < 4; ++j) {
            int f = tid + j * 256;
            float kk = ks[f >> 4];
            float4 vv = *(const float4*)&vs[(f & 15) * 4];
            float4 r;
            r.x = fmaf(decay, p4[j].x, kk * vv.x);
            r.y = fmaf(decay, p4[j].y, kk * vv.y);
            r.z = fmaf(decay, p4[j].z, kk * vv.z);
            r.w = fmaf(decay, p4[j].w, kk * vv.w);
            *(float4*)&co[(size_t)pos * 4096 + f * 4] = r;
        }
    }

    // out: thread handles vd = tid&63, positions wave, wave+4, wave+8, wave+12
    const int wave = tid >> 6, vd = tid & 63;
    float accs[4] = {0.0f, 0.0f, 0.0f, 0.0f};
    for (int kd = 0; kd < 64; ++kd) {
        float pv = pkv_s[kd * 64 + vd];
        #pragma unroll
        for (int pp = 0; pp < 4; ++pp)
            accs[pp] = fmaf(qkv_s[(wave + pp * 4) * NQKV + kd], pv, accs[pp]);
    }
    float s1 = 0.0f, s2 = 0.0f;
    #pragma unroll
    for (int pp = 0; pp < 4; ++pp) {
        int pos = wave + pp * 4;
        float o = fmaf(decay, accs[pp],
                       qk_s[pos] * qkv_s[pos * NQKV + 128 + vd]);
        out_pre[(size_t)(bn * L + pos0 + pos) * D + vd] = o;
        s1 += o; s2 += o * o;
    }

    // block-level partial sums
    r1[tid] = s1; r2[tid] = s2;
    __syncthreads();
    for (int off = 128; off; off >>= 1) {
        if (tid < off) { r1[tid] += r1[tid + off]; r2[tid] += r2[tid + off]; }
        __syncthreads();
    }
    if (tid == 0) {
        partials[(size_t)blk * 2]     = r1[0];
        partials[(size_t)blk * 2 + 1] = r2[0];
    }
}

// ---------------------------------------------------------------------------
// Kernel 3: per-group (b,n) reduction: 64 blocks per group, one wave per group
// ---------------------------------------------------------------------------
__global__ __launch_bounds__(64) void group_reduce_kernel(
    const float* __restrict__ partials, float* __restrict__ stats)
{
    const int g   = blockIdx.x;   // 0..31
    const int tid = threadIdx.x;  // 0..63
    float s1 = partials[(size_t)(g * 64 + tid) * 2];
    float s2 = partials[(size_t)(g * 64 + tid) * 2 + 1];
    #pragma unroll
    for (int off = 32; off; off >>= 1) {
        s1 += __shfl_down(s1, off);
        s2 += __shfl_down(s2, off);
    }
    if (tid == 0) {
        const float cnt = (float)(L * D);
        float mean = s1 / cnt;
        float var  = s2 / cnt - mean * mean;
        stats[g * 2]     = mean;
        stats[g * 2 + 1] = rsqrtf(var + EPS);
    }
}

// ---------------------------------------------------------------------------
// Kernel 4: in-place normalize (float4)
// ---------------------------------------------------------------------------
__global__ __launch_bounds__(256) void normalize_kernel(
    float* __restrict__ out, const float* __restrict__ stats)
{
    int idx = blockIdx.x * 256 + threadIdx.x;   // float4 index
    int g = idx >> 14;                          // 16384 float4 per group
    float mean = stats[g * 2];
    float rstd = stats[g * 2 + 1];
    float4 v = ((const float4*)out)[idx];
    v.x = (v.x - mean) * rstd; v.y = (v.y - mean) * rstd;
    v.z = (v.z - mean) * rstd; v.w = (v.w - mean) * rstd;
    ((float4*)out)[idx] = v;
}

// ---------------------------------------------------------------------------
extern "C" void kernel_launch(void* const* d_in, const int* in_sizes, int n_in,
                              void* d_out, int out_size, void* d_ws, size_t ws_size,
                              hipStream_t stream)
{
    const float* x       = (const float*)d_in[0];
    const float* past_kv = (const float*)d_in[1];
    const float* Wq      = (const float*)d_in[2];
    const float* bq      = (const float*)d_in[3];
    const float* Wk      = (const float*)d_in[4];
    const float* bk      = (const float*)d_in[5];
    const float* Wv      = (const float*)d_in[6];
    const float* bv      = (const float*)d_in[7];

    float* out = (float*)d_out;                    // [M*64]
    float* ckv = out + (size_t)M * 64;             // [M*4096]

    // Wb (bf16 weights) in the TAIL of ckv output: proj reads before retention
    // overwrites (stream order). Zero extra ws.
    unsigned short* Wb = (unsigned short*)(ckv + (size_t)M * 4096) - (size_t)NQKV * E;

    float* qkv      = (float*)d_ws;                // M*192 floats
    float* partials = qkv + (size_t)M * 192;       // NBLKS*2
    float* stats    = partials + (size_t)NBLKS * 2;

    convw_kernel<<<96, 256, 0, stream>>>(Wq, Wk, Wv, Wb);
    proj_mfma_kernel<<<M / 128, 512, 0, stream>>>(x, Wb, bq, bk, bv, qkv);
    retention_kernel<<<NBLKS, 256, 0, stream>>>(qkv, past_kv, out, ckv, partials);
    group_reduce_kernel<<<32, 64, 0, stream>>>(partials, stats);
    normalize_kernel<<<(M * 16) / 256, 256, 0, stream>>>(out, stats);
}